// Round 1
// baseline (276.655 us; speedup 1.0000x reference)
//
#include <hip/hip_runtime.h>

constexpr int NKD = 64;    // node key dim
constexpr int EKD = 16;    // edge key dim
constexpr int QD  = 80;    // NKD + EKD
constexpr int NN  = 256;   // sequence length
constexpr int DVD = 64;    // value dim
constexpr int BB  = 4;
constexpr int HH  = 8;

// One block per (b,h,q) row. 256 threads = 4 waves; thread tid owns key index k=tid.
__global__ __launch_bounds__(256) void sdpe_kernel(
    const float* __restrict__ q, const float* __restrict__ nk,
    const float* __restrict__ ek, const float* __restrict__ v,
    const int* __restrict__ mask, float* __restrict__ out, float* __restrict__ attn_out)
{
    const int row  = blockIdx.x;          // (b*H + h)*N + qi
    const int bh   = row >> 8;            // b*H + h
    const int qi   = row & (NN - 1);
    const int b    = bh >> 3;             // H == 8
    const int tid  = threadIdx.x;         // key index k
    const int wave = tid >> 6;
    const int lane = tid & 63;

    __shared__ float s_attn[NN];
    __shared__ float s_redmax[4];
    __shared__ float s_redsum[4];
    __shared__ float s_part[4][DVD];

    const float* qrow  = q  + (size_t)row * QD;                  // block-uniform
    const float* nkrow = nk + ((size_t)bh * NN + tid) * NKD;
    const float* ekrow = ek + ((size_t)row * NN + tid) * EKD;

    // ---- scores: node + edge ----
    float acc = 0.f;
    #pragma unroll
    for (int j = 0; j < NKD; j += 4) {
        const float4 a  = *(const float4*)(qrow + j);
        const float4 bb = *(const float4*)(nkrow + j);
        acc += a.x * bb.x + a.y * bb.y + a.z * bb.z + a.w * bb.w;
    }
    #pragma unroll
    for (int j = 0; j < EKD; j += 4) {
        const float4 a = *(const float4*)(qrow + NKD + j);
        const float4 e = *(const float4*)(ekrow + j);
        acc += a.x * e.x + a.y * e.y + a.z * e.z + a.w * e.w;
    }
    acc *= 0.125f;  // 1/TEMPERATURE

    const int m = mask[((size_t)b * NN + qi) * NN + tid];  // mask shape (B,1,N,N)
    if (m == 0) acc = -1.0e9f;

    // ---- softmax over k (256 threads) ----
    float mx = acc;
    #pragma unroll
    for (int o = 32; o >= 1; o >>= 1) mx = fmaxf(mx, __shfl_xor(mx, o));
    if (lane == 0) s_redmax[wave] = mx;
    __syncthreads();
    const float rmax = fmaxf(fmaxf(s_redmax[0], s_redmax[1]),
                             fmaxf(s_redmax[2], s_redmax[3]));

    const float p = __expf(acc - rmax);
    float sm = p;
    #pragma unroll
    for (int o = 32; o >= 1; o >>= 1) sm += __shfl_xor(sm, o);
    if (lane == 0) s_redsum[wave] = sm;
    __syncthreads();
    const float rsum = s_redsum[0] + s_redsum[1] + s_redsum[2] + s_redsum[3];

    const float a_final = p / rsum;
    s_attn[tid] = a_final;
    attn_out[(size_t)row * NN + tid] = a_final;   // second tuple output
    __syncthreads();

    // ---- PV: out[d] = sum_k attn[k] * v[bh,k,d] ----
    // wave g handles k in [64g, 64g+64); lane = output dim d.
    const float* vb = v + (size_t)bh * NN * DVD + (size_t)wave * 64 * DVD + lane;
    float oacc = 0.f;
    #pragma unroll
    for (int kk = 0; kk < 64; kk += 4) {
        const float4 a4 = *(const float4*)(&s_attn[wave * 64 + kk]);  // wave-uniform broadcast
        oacc += a4.x * vb[(kk + 0) * DVD];
        oacc += a4.y * vb[(kk + 1) * DVD];
        oacc += a4.z * vb[(kk + 2) * DVD];
        oacc += a4.w * vb[(kk + 3) * DVD];
    }
    s_part[wave][lane] = oacc;
    __syncthreads();
    if (tid < DVD) {
        out[(size_t)row * DVD + tid] =
            s_part[0][tid] + s_part[1][tid] + s_part[2][tid] + s_part[3][tid];
    }
}

extern "C" void kernel_launch(void* const* d_in, const int* in_sizes, int n_in,
                              void* d_out, int out_size, void* d_ws, size_t ws_size,
                              hipStream_t stream) {
    const float* q    = (const float*)d_in[0];
    const float* nk   = (const float*)d_in[1];
    const float* ek   = (const float*)d_in[2];
    const float* v    = (const float*)d_in[3];
    const int*   mask = (const int*)d_in[4];

    float* out      = (float*)d_out;
    float* attn_out = out + (size_t)BB * HH * NN * DVD;   // tuple: (output, attn) flat

    const int nblocks = BB * HH * NN;   // 8192
    sdpe_kernel<<<nblocks, 256, 0, stream>>>(q, nk, ek, v, mask, out, attn_out);
}

// Round 2
// 214.024 us; speedup vs baseline: 1.2926x; 1.2926x over previous
//
#include <hip/hip_runtime.h>

constexpr int NKD = 64;    // node key dim
constexpr int EKD = 16;    // edge key dim
constexpr int QD  = 80;    // NKD + EKD
constexpr int NN  = 256;   // sequence length
constexpr int DVD = 64;    // value dim
constexpr int BB  = 4;
constexpr int HH  = 8;
constexpr int QT  = 16;    // q rows per block
constexpr int NT  = 256;   // threads per block

// Grid: 32 (b,h) pairs x 16 q-tiles = 512 blocks, 256 threads each.
// Thread tid owns key k = tid for the score phase (nk row cached in regs,
// reused across all 16 q rows of the tile).
__global__ __launch_bounds__(256) void sdpe_kernel(
    const float* __restrict__ q, const float* __restrict__ nk,
    const float* __restrict__ ek, const float* __restrict__ v,
    const int* __restrict__ mask, float* __restrict__ out, float* __restrict__ attn_out)
{
    const int bid  = blockIdx.x;
    const int bh   = bid >> 4;            // (b*H + h)
    const int q0   = (bid & 15) * QT;
    const int b    = bh >> 3;             // H == 8
    const int tid  = threadIdx.x;         // key index k in score phase
    const int wave = tid >> 6;
    const int lane = tid & 63;

    __shared__ float s_q[QT * QD];        // 5.1 KB  staged q tile
    __shared__ float s_S[QT * NN];        // 16 KB   scores -> attn (in place)

    // ---- stage q tile (coalesced float4) ----
    {
        const float4* qsrc = (const float4*)(q + ((size_t)bh * NN + q0) * QD);
        float4*       qdst = (float4*)s_q;
        for (int i = tid; i < QT * QD / 4; i += NT) qdst[i] = qsrc[i];
    }

    // ---- cache this thread's nk row in registers (divergent load, ONCE) ----
    float4 nkr[16];
    {
        const float4* nkp = (const float4*)(nk + ((size_t)bh * NN + tid) * NKD);
        #pragma unroll
        for (int j = 0; j < 16; ++j) nkr[j] = nkp[j];
    }
    __syncthreads();

    // ---- scores for all 16 rows ----
    #pragma unroll
    for (int r = 0; r < QT; ++r) {
        const size_t rowg = (size_t)bh * NN + q0 + r;
        const float4* qr  = (const float4*)(s_q + r * QD);   // broadcast reads
        float acc = 0.f;
        #pragma unroll
        for (int j = 0; j < 16; ++j) {
            const float4 a = qr[j], n = nkr[j];
            acc += a.x * n.x + a.y * n.y + a.z * n.z + a.w * n.w;
        }
        const float4* ekp = (const float4*)(ek + (rowg * NN + tid) * EKD);
        #pragma unroll
        for (int j = 0; j < 4; ++j) {
            const float4 a = qr[16 + j], e = ekp[j];
            acc += a.x * e.x + a.y * e.y + a.z * e.z + a.w * e.w;
        }
        acc *= 0.125f;  // 1/TEMPERATURE
        if (mask[((size_t)b * NN + q0 + r) * NN + tid] == 0) acc = -1.0e9f;
        s_S[r * NN + tid] = acc;
    }
    __syncthreads();

    // ---- softmax: wave w handles rows 4w..4w+3, pure wave-shuffle ----
    #pragma unroll
    for (int rr = 0; rr < 4; ++rr) {
        const int r = wave * 4 + rr;
        float4 f = *(const float4*)&s_S[r * NN + lane * 4];
        float mx = fmaxf(fmaxf(f.x, f.y), fmaxf(f.z, f.w));
        #pragma unroll
        for (int o = 32; o >= 1; o >>= 1) mx = fmaxf(mx, __shfl_xor(mx, o));
        float4 e;
        e.x = __expf(f.x - mx); e.y = __expf(f.y - mx);
        e.z = __expf(f.z - mx); e.w = __expf(f.w - mx);
        float s = e.x + e.y + e.z + e.w;
        #pragma unroll
        for (int o = 32; o >= 1; o >>= 1) s += __shfl_xor(s, o);
        const float inv = 1.f / s;
        e.x *= inv; e.y *= inv; e.z *= inv; e.w *= inv;
        *(float4*)&s_S[r * NN + lane * 4] = e;                       // in-place A
        const size_t rowg = (size_t)bh * NN + q0 + r;
        *(float4*)(attn_out + rowg * NN + lane * 4) = e;             // coalesced
    }
    __syncthreads();

    // ---- PV: wave w owns rows 4w..4w+3; lane = (kg, d4) ----
    // v loads: wave covers 4 consecutive k rows x all 64 d = 1 KB contiguous.
    const int d4 = lane & 15;       // d block (4 floats)
    const int kg = lane >> 4;       // k phase 0..3
    const int r0 = wave * 4;
    float4 acc[4];
    #pragma unroll
    for (int rr = 0; rr < 4; ++rr) acc[rr] = make_float4(0.f, 0.f, 0.f, 0.f);

    const float* vb = v + (size_t)bh * NN * DVD + d4 * 4;
    #pragma unroll 4
    for (int k = kg; k < NN; k += 4) {
        const float4 v4 = *(const float4*)(vb + (size_t)k * DVD);
        #pragma unroll
        for (int rr = 0; rr < 4; ++rr) {
            const float a = s_S[(r0 + rr) * NN + k];   // 16-lane broadcast
            acc[rr].x += a * v4.x; acc[rr].y += a * v4.y;
            acc[rr].z += a * v4.z; acc[rr].w += a * v4.w;
        }
    }
    // reduce across the 4 kg groups (lanes xor 16, 32)
    #pragma unroll
    for (int rr = 0; rr < 4; ++rr) {
        acc[rr].x += __shfl_xor(acc[rr].x, 16);
        acc[rr].y += __shfl_xor(acc[rr].y, 16);
        acc[rr].z += __shfl_xor(acc[rr].z, 16);
        acc[rr].w += __shfl_xor(acc[rr].w, 16);
        acc[rr].x += __shfl_xor(acc[rr].x, 32);
        acc[rr].y += __shfl_xor(acc[rr].y, 32);
        acc[rr].z += __shfl_xor(acc[rr].z, 32);
        acc[rr].w += __shfl_xor(acc[rr].w, 32);
    }
    if (kg == 0) {
        #pragma unroll
        for (int rr = 0; rr < 4; ++rr) {
            const size_t rowg = (size_t)bh * NN + q0 + r0 + rr;
            *(float4*)(out + rowg * DVD + d4 * 4) = acc[rr];
        }
    }
}

extern "C" void kernel_launch(void* const* d_in, const int* in_sizes, int n_in,
                              void* d_out, int out_size, void* d_ws, size_t ws_size,
                              hipStream_t stream) {
    const float* q    = (const float*)d_in[0];
    const float* nk   = (const float*)d_in[1];
    const float* ek   = (const float*)d_in[2];
    const float* v    = (const float*)d_in[3];
    const int*   mask = (const int*)d_in[4];

    float* out      = (float*)d_out;
    float* attn_out = out + (size_t)BB * HH * NN * DVD;   // tuple: (output, attn)

    const int nblocks = BB * HH * (NN / QT);   // 512
    sdpe_kernel<<<nblocks, NT, 0, stream>>>(q, nk, ek, v, mask, out, attn_out);
}